// Round 7
// baseline (231.051 us; speedup 1.0000x reference)
//
#include <hip/hip_runtime.h>

// Trilinear feature-grid interpolation, v3.
// grid layout: [R][R][R][3] = [z][y][x][c], R=256, fp32 (192 MB).
//
// Two passes:
//  1) k_scatter: bin points into 4096 fixed-capacity bins (64x8x8 cells),
//     global atomic counters, inline direct-gather fallback on overflow
//     (CAP = 2x mean; statistically never taken).
//  2) k_gather: one block per bin; stage the bin's 65x9x9-cell corner slab
//     (63.5 KB) into LDS via global_load_lds width=16 (fire-and-forget DMA,
//     LDS-linear float4 stream), then trilerp all bin points from LDS.

#define NB     4096
#define CAP    1024u
#define GBLK   512
#define CHUNKF 196                // floats per x-chunk (49 float4, no pad)
#define NCHUNK 81                 // 9 z-rows x 9 y-rows
#define NF4    (NCHUNK * 49)      // 3969 float4 per slab
#define LDSF   (NF4 * 4)          // 15876 floats = 63504 B
#define CNT_OFF 67108864u         // after binned[4096*1024] float4
#define NEEDED  (67108864u + 16384u)

typedef float f4v __attribute__((ext_vector_type(4)));
typedef float f2v __attribute__((ext_vector_type(2)));
typedef f4v f4u __attribute__((aligned(8)));
typedef f2v f2u __attribute__((aligned(8)));

__device__ __forceinline__ void cell_of(float p, int& l, float& t) {
    float s = p * 255.0f;
    int v = (int)floorf(s);
    v = v < 0 ? 0 : (v > 254 ? 254 : v);
    l = v;
    t = s - (float)v;
}

// bin bits: [zb:5][yb:5][xb:2]  (64x8x8 cells per bin)
__device__ __forceinline__ int fine_bin(int xl, int yl, int zl) {
    return ((((zl >> 3) << 5) | (yl >> 3)) << 2) | (xl >> 6);
}

__device__ __forceinline__ void direct_lerp(const float* __restrict__ grid,
                                            float* __restrict__ out, int i,
                                            int xl, int yl, int zl,
                                            float tx, float ty, float tz) {
    int b00 = (zl * 65536 + yl * 256 + xl) * 3;
    int b01 = b00 + 768, b10 = b00 + 196608, b11 = b10 + 768;
    float s00[6], s01[6], s10[6], s11[6];
#pragma unroll
    for (int k = 0; k < 6; ++k) s00[k] = grid[b00 + k];
#pragma unroll
    for (int k = 0; k < 6; ++k) s01[k] = grid[b01 + k];
#pragma unroll
    for (int k = 0; k < 6; ++k) s10[k] = grid[b10 + k];
#pragma unroll
    for (int k = 0; k < 6; ++k) s11[k] = grid[b11 + k];
#pragma unroll
    for (int c = 0; c < 3; ++c) {
        float c00 = s00[c] * (1.0f - tx) + s00[c + 3] * tx;
        float c01 = s01[c] * (1.0f - tx) + s01[c + 3] * tx;
        float c10 = s10[c] * (1.0f - tx) + s10[c + 3] * tx;
        float c11 = s11[c] * (1.0f - tx) + s11[c + 3] * tx;
        float c0 = c00 * (1.0f - ty) + c01 * ty;
        float c1 = c10 * (1.0f - ty) + c11 * ty;
        out[3 * i + c] = c0 * (1.0f - tz) + c1 * tz;
    }
}

// ---------------- pass 1: fixed-capacity scatter ----------------
__global__ __launch_bounds__(1024) void k_scatter(const float* __restrict__ inp,
                                                  const float* __restrict__ grid,
                                                  float4* __restrict__ binned,
                                                  unsigned* __restrict__ cnt,
                                                  float* __restrict__ out, int n) {
    int stride = gridDim.x * 1024;
    for (int i = blockIdx.x * 1024 + threadIdx.x; i < n; i += stride) {
        float px = inp[3 * i], py = inp[3 * i + 1], pz = inp[3 * i + 2];
        int xl, yl, zl; float tx, ty, tz;
        cell_of(px, xl, tx);
        cell_of(py, yl, ty);
        cell_of(pz, zl, tz);
        int b = fine_bin(xl, yl, zl);
        unsigned r = atomicAdd(&cnt[b], 1u);
        if (r < CAP) {
            float4 v;
            v.x = px; v.y = py; v.z = pz; v.w = __uint_as_float((unsigned)i);
            binned[(unsigned)b * CAP + r] = v;
        } else {
            // overflow: compute directly (statistically never taken)
            direct_lerp(grid, out, i, xl, yl, zl, tx, ty, tz);
        }
    }
}

// ---------------- pass 2: LDS-staged gather / trilerp ----------------
__global__ __launch_bounds__(GBLK) void k_gather(const float4* __restrict__ binned,
                                                 const float* __restrict__ grid,
                                                 const unsigned* __restrict__ cnt,
                                                 float* __restrict__ out) {
    __shared__ __align__(16) float slab[LDSF];
    int bin = blockIdx.x;
    int x0 = (bin & 3) << 6;          // 0,64,128,192
    int y0 = ((bin >> 2) & 31) << 3;  // 0..248
    int z0 = (bin >> 7) << 3;         // 0..248
    int t = threadIdx.x;

    unsigned count = cnt[bin];
    if (count > CAP) count = CAP;
    unsigned base = (unsigned)bin * CAP;

    // Prefetch this thread's first point while staging is in flight.
    float4 v;
    bool have = (unsigned)t < count;
    if (have) v = binned[base + (unsigned)t];

    // Stage 3969 float4 (81 chunks x 49) as an LDS-linear stream via
    // global_load_lds: dest = wave-uniform base + lane*16 by construction.
    for (int u0 = 0; u0 < NF4; u0 += GBLK) {
        int u = u0 + t;
        if (u < NF4) {
            int chunk = u / 49;
            int j = u - chunk * 49;
            int zc = chunk / 9;
            int yc = chunk - zc * 9;
            int zg = z0 + zc; zg = zg > 255 ? 255 : zg;   // clamped rows unread
            int yg = y0 + yc; yg = yg > 255 ? 255 : yg;
            // x0=192,j=48 would read 16B past the grid; those 4 floats are
            // never consumed (cells x>=256 don't exist) -> clamp SOURCE only,
            // keeping the LDS destination stream linear.
            int joff = (j == 48 && x0 == 192) ? 0 : (j << 2);
            const float* src = grid + (size_t)((zg << 16) | (yg << 8) | x0) * 3 + joff;
            __builtin_amdgcn_global_load_lds(
                (const __attribute__((address_space(1))) unsigned int*)src,
                (__attribute__((address_space(3))) unsigned int*)&slab[(size_t)u * 4],
                16, 0, 0);
        }
    }
    __syncthreads();

    unsigned p = (unsigned)t;
    while (p < count) {
        float px = v.x, py = v.y, pz = v.z;
        unsigned idx = __float_as_uint(v.w);
        p += (unsigned)GBLK;
        if (p < count) v = binned[base + p];   // prefetch next iteration

        int xl, yl, zl; float tx, ty, tz;
        cell_of(px, xl, tx);
        cell_of(py, yl, ty);
        cell_of(pz, zl, tz);
        int xc = xl - x0, yc = yl - y0, zc = zl - z0;

        int r0 = (zc * 9 + yc) * CHUNKF + xc * 3;
        int e = r0 & ~1;
        bool d = (r0 & 1) != 0;

#define SEG_READ(b, s)                                   \
        do {                                             \
            f2v q0 = *(const f2u*)(&slab[(b)]);          \
            f2v q1 = *(const f2u*)(&slab[(b) + 2]);      \
            f2v q2 = *(const f2u*)(&slab[(b) + 4]);      \
            f2v q3 = *(const f2u*)(&slab[(b) + 6]);      \
            s[0] = d ? q0.y : q0.x;                      \
            s[1] = d ? q1.x : q0.y;                      \
            s[2] = d ? q1.y : q1.x;                      \
            s[3] = d ? q2.x : q1.y;                      \
            s[4] = d ? q2.y : q2.x;                      \
            s[5] = d ? q3.x : q2.y;                      \
        } while (0)

        float s00[6], s01[6], s10[6], s11[6];
        SEG_READ(e,               s00);   // (zc,   yc)
        SEG_READ(e + CHUNKF,      s01);   // (zc,   yc+1)
        SEG_READ(e + 9 * CHUNKF,  s10);   // (zc+1, yc)
        SEG_READ(e + 10 * CHUNKF, s11);   // (zc+1, yc+1)
#undef SEG_READ

        float o[3];
#pragma unroll
        for (int c = 0; c < 3; ++c) {
            float c00 = s00[c] * (1.0f - tx) + s00[c + 3] * tx;
            float c01 = s01[c] * (1.0f - tx) + s01[c + 3] * tx;
            float c10 = s10[c] * (1.0f - tx) + s10[c + 3] * tx;
            float c11 = s11[c] * (1.0f - tx) + s11[c + 3] * tx;
            float c0 = c00 * (1.0f - ty) + c01 * ty;
            float c1 = c10 * (1.0f - ty) + c11 * ty;
            o[c] = c0 * (1.0f - tz) + c1 * tz;
        }
        float3 w; w.x = o[0]; w.y = o[1]; w.z = o[2];
        *(float3*)(out + 3 * (size_t)idx) = w;   // single store inst
    }
}

// ---------------- fallback: direct ----------------
__global__ __launch_bounds__(256) void k_direct(const float* __restrict__ inp,
                                                const float* __restrict__ grid,
                                                float* __restrict__ out, int n) {
    int i = blockIdx.x * blockDim.x + threadIdx.x;
    if (i >= n) return;
    int xl, yl, zl; float tx, ty, tz;
    cell_of(inp[3 * i + 0], xl, tx);
    cell_of(inp[3 * i + 1], yl, ty);
    cell_of(inp[3 * i + 2], zl, tz);
    direct_lerp(grid, out, i, xl, yl, zl, tx, ty, tz);
}

extern "C" void kernel_launch(void* const* d_in, const int* in_sizes, int n_in,
                              void* d_out, int out_size, void* d_ws, size_t ws_size,
                              hipStream_t stream) {
    const float* inp  = (const float*)d_in[0];  // [N][3]
    const float* grid = (const float*)d_in[1];  // [256][256][256][3]
    float* out = (float*)d_out;                 // [N][3]
    int n = in_sizes[0] / 3;

    if (ws_size < (size_t)NEEDED) {
        int blocks = (n + 255) / 256;
        k_direct<<<blocks, 256, 0, stream>>>(inp, grid, out, n);
        return;
    }

    char* ws = (char*)d_ws;
    float4*   binned = (float4*)ws;
    unsigned* cnt    = (unsigned*)(ws + CNT_OFF);

    hipMemsetAsync(cnt, 0, NB * sizeof(unsigned), stream);
    k_scatter<<<2048, 1024, 0, stream>>>(inp, grid, binned, cnt, out, n);
    k_gather <<<NB,   GBLK, 0, stream>>>(binned, grid, cnt, out);
}

// Round 8
// 230.718 us; speedup vs baseline: 1.0014x; 1.0014x over previous
//
#include <hip/hip_runtime.h>

// Trilinear feature-grid interpolation, v4.
// grid layout: [R][R][R][3] = [z][y][x][c], R=256, fp32 (192 MB).
//
// Round-7 evidence: fixed-cap strided bins (binned[b*1024+r]) with
// globally-synchronized cursors put all concurrent 16B writes on a pure
// 16KB-strided address set -> HBM channel serialization (125 MB at 0.85
// TB/s = the entire 150 us scatter). Fix: per-bin slot rotation
// slot = (hash(b) + r) & 1023 decorrelates concurrent addresses across
// channels while keeping each bin's records contiguous (mod wrap) for the
// gather. k_gather (global_load_lds slab staging, ~78 us) unchanged.

#define NB     4096
#define CAP    1024u
#define GBLK   512
#define CHUNKF 196                // floats per x-chunk (49 float4, no pad)
#define NCHUNK 81                 // 9 z-rows x 9 y-rows
#define NF4    (NCHUNK * 49)      // 3969 float4 per slab
#define LDSF   (NF4 * 4)          // 15876 floats = 63504 B
#define CNT_OFF 67108864u         // after binned[4096*1024] float4
#define NEEDED  (67108864u + 16384u)

typedef float f4v __attribute__((ext_vector_type(4)));
typedef float f2v __attribute__((ext_vector_type(2)));
typedef f4v f4u __attribute__((aligned(8)));
typedef f2v f2u __attribute__((aligned(8)));

__device__ __forceinline__ void cell_of(float p, int& l, float& t) {
    float s = p * 255.0f;
    int v = (int)floorf(s);
    v = v < 0 ? 0 : (v > 254 ? 254 : v);
    l = v;
    t = s - (float)v;
}

// bin bits: [zb:5][yb:5][xb:2]  (64x8x8 cells per bin)
__device__ __forceinline__ int fine_bin(int xl, int yl, int zl) {
    return ((((zl >> 3) << 5) | (yl >> 3)) << 2) | (xl >> 6);
}

__device__ __forceinline__ unsigned bin_rot(int b) {
    return ((unsigned)b * 2654435761u) >> 22;   // 10-bit per-bin start offset
}

__device__ __forceinline__ void direct_lerp(const float* __restrict__ grid,
                                            float* __restrict__ out, int i,
                                            int xl, int yl, int zl,
                                            float tx, float ty, float tz) {
    int b00 = (zl * 65536 + yl * 256 + xl) * 3;
    int b01 = b00 + 768, b10 = b00 + 196608, b11 = b10 + 768;
    float s00[6], s01[6], s10[6], s11[6];
#pragma unroll
    for (int k = 0; k < 6; ++k) s00[k] = grid[b00 + k];
#pragma unroll
    for (int k = 0; k < 6; ++k) s01[k] = grid[b01 + k];
#pragma unroll
    for (int k = 0; k < 6; ++k) s10[k] = grid[b10 + k];
#pragma unroll
    for (int k = 0; k < 6; ++k) s11[k] = grid[b11 + k];
#pragma unroll
    for (int c = 0; c < 3; ++c) {
        float c00 = s00[c] * (1.0f - tx) + s00[c + 3] * tx;
        float c01 = s01[c] * (1.0f - tx) + s01[c + 3] * tx;
        float c10 = s10[c] * (1.0f - tx) + s10[c + 3] * tx;
        float c11 = s11[c] * (1.0f - tx) + s11[c + 3] * tx;
        float c0 = c00 * (1.0f - ty) + c01 * ty;
        float c1 = c10 * (1.0f - ty) + c11 * ty;
        out[3 * i + c] = c0 * (1.0f - tz) + c1 * tz;
    }
}

// ---------------- pass 1: fixed-capacity scatter (rotated slots) ----------------
__global__ __launch_bounds__(1024) void k_scatter(const float* __restrict__ inp,
                                                  const float* __restrict__ grid,
                                                  float4* __restrict__ binned,
                                                  unsigned* __restrict__ cnt,
                                                  float* __restrict__ out, int n) {
    int stride = gridDim.x * 1024;
    for (int i = blockIdx.x * 1024 + threadIdx.x; i < n; i += stride) {
        float px = inp[3 * i], py = inp[3 * i + 1], pz = inp[3 * i + 2];
        int xl, yl, zl; float tx, ty, tz;
        cell_of(px, xl, tx);
        cell_of(py, yl, ty);
        cell_of(pz, zl, tz);
        int b = fine_bin(xl, yl, zl);
        unsigned r = atomicAdd(&cnt[b], 1u);
        if (r < CAP) {
            unsigned slot = (bin_rot(b) + r) & (CAP - 1u);
            float4 v;
            v.x = px; v.y = py; v.z = pz; v.w = __uint_as_float((unsigned)i);
            binned[(unsigned)b * CAP + slot] = v;
        } else {
            // overflow: compute directly (statistically never taken)
            direct_lerp(grid, out, i, xl, yl, zl, tx, ty, tz);
        }
    }
}

// ---------------- pass 2: LDS-staged gather / trilerp ----------------
__global__ __launch_bounds__(GBLK) void k_gather(const float4* __restrict__ binned,
                                                 const float* __restrict__ grid,
                                                 const unsigned* __restrict__ cnt,
                                                 float* __restrict__ out) {
    __shared__ __align__(16) float slab[LDSF];
    int bin = blockIdx.x;
    int x0 = (bin & 3) << 6;          // 0,64,128,192
    int y0 = ((bin >> 2) & 31) << 3;  // 0..248
    int z0 = (bin >> 7) << 3;         // 0..248
    int t = threadIdx.x;

    unsigned count = cnt[bin];
    if (count > CAP) count = CAP;
    unsigned base = (unsigned)bin * CAP;
    unsigned rot  = bin_rot(bin);

    // Prefetch this thread's first point while staging is in flight.
    float4 v;
    if ((unsigned)t < count) v = binned[base + ((rot + (unsigned)t) & (CAP - 1u))];

    // Stage 3969 float4 (81 chunks x 49) as an LDS-linear stream via
    // global_load_lds: dest = wave-uniform base + lane*16 by construction.
    for (int u0 = 0; u0 < NF4; u0 += GBLK) {
        int u = u0 + t;
        if (u < NF4) {
            int chunk = u / 49;
            int j = u - chunk * 49;
            int zc = chunk / 9;
            int yc = chunk - zc * 9;
            int zg = z0 + zc; zg = zg > 255 ? 255 : zg;   // clamped rows unread
            int yg = y0 + yc; yg = yg > 255 ? 255 : yg;
            // x0=192,j=48 would read 16B past the grid; those 4 floats are
            // never consumed (cells x>=256 don't exist) -> clamp SOURCE only,
            // keeping the LDS destination stream linear.
            int joff = (j == 48 && x0 == 192) ? 0 : (j << 2);
            const float* src = grid + (size_t)((zg << 16) | (yg << 8) | x0) * 3 + joff;
            __builtin_amdgcn_global_load_lds(
                (const __attribute__((address_space(1))) unsigned int*)src,
                (__attribute__((address_space(3))) unsigned int*)&slab[(size_t)u * 4],
                16, 0, 0);
        }
    }
    __syncthreads();

    unsigned p = (unsigned)t;
    while (p < count) {
        float px = v.x, py = v.y, pz = v.z;
        unsigned idx = __float_as_uint(v.w);
        p += (unsigned)GBLK;
        if (p < count) v = binned[base + ((rot + p) & (CAP - 1u))];  // prefetch next

        int xl, yl, zl; float tx, ty, tz;
        cell_of(px, xl, tx);
        cell_of(py, yl, ty);
        cell_of(pz, zl, tz);
        int xc = xl - x0, yc = yl - y0, zc = zl - z0;

        int r0 = (zc * 9 + yc) * CHUNKF + xc * 3;
        int e = r0 & ~1;
        bool d = (r0 & 1) != 0;

#define SEG_READ(b, s)                                   \
        do {                                             \
            f2v q0 = *(const f2u*)(&slab[(b)]);          \
            f2v q1 = *(const f2u*)(&slab[(b) + 2]);      \
            f2v q2 = *(const f2u*)(&slab[(b) + 4]);      \
            f2v q3 = *(const f2u*)(&slab[(b) + 6]);      \
            s[0] = d ? q0.y : q0.x;                      \
            s[1] = d ? q1.x : q0.y;                      \
            s[2] = d ? q1.y : q1.x;                      \
            s[3] = d ? q2.x : q1.y;                      \
            s[4] = d ? q2.y : q2.x;                      \
            s[5] = d ? q3.x : q2.y;                      \
        } while (0)

        float s00[6], s01[6], s10[6], s11[6];
        SEG_READ(e,               s00);   // (zc,   yc)
        SEG_READ(e + CHUNKF,      s01);   // (zc,   yc+1)
        SEG_READ(e + 9 * CHUNKF,  s10);   // (zc+1, yc)
        SEG_READ(e + 10 * CHUNKF, s11);   // (zc+1, yc+1)
#undef SEG_READ

        float o[3];
#pragma unroll
        for (int c = 0; c < 3; ++c) {
            float c00 = s00[c] * (1.0f - tx) + s00[c + 3] * tx;
            float c01 = s01[c] * (1.0f - tx) + s01[c + 3] * tx;
            float c10 = s10[c] * (1.0f - tx) + s10[c + 3] * tx;
            float c11 = s11[c] * (1.0f - tx) + s11[c + 3] * tx;
            float c0 = c00 * (1.0f - ty) + c01 * ty;
            float c1 = c10 * (1.0f - ty) + c11 * ty;
            o[c] = c0 * (1.0f - tz) + c1 * tz;
        }
        float3 w; w.x = o[0]; w.y = o[1]; w.z = o[2];
        *(float3*)(out + 3 * (size_t)idx) = w;   // single store inst
    }
}

// ---------------- fallback: direct ----------------
__global__ __launch_bounds__(256) void k_direct(const float* __restrict__ inp,
                                                const float* __restrict__ grid,
                                                float* __restrict__ out, int n) {
    int i = blockIdx.x * blockDim.x + threadIdx.x;
    if (i >= n) return;
    int xl, yl, zl; float tx, ty, tz;
    cell_of(inp[3 * i + 0], xl, tx);
    cell_of(inp[3 * i + 1], yl, ty);
    cell_of(inp[3 * i + 2], zl, tz);
    direct_lerp(grid, out, i, xl, yl, zl, tx, ty, tz);
}

extern "C" void kernel_launch(void* const* d_in, const int* in_sizes, int n_in,
                              void* d_out, int out_size, void* d_ws, size_t ws_size,
                              hipStream_t stream) {
    const float* inp  = (const float*)d_in[0];  // [N][3]
    const float* grid = (const float*)d_in[1];  // [256][256][256][3]
    float* out = (float*)d_out;                 // [N][3]
    int n = in_sizes[0] / 3;

    if (ws_size < (size_t)NEEDED) {
        int blocks = (n + 255) / 256;
        k_direct<<<blocks, 256, 0, stream>>>(inp, grid, out, n);
        return;
    }

    char* ws = (char*)d_ws;
    float4*   binned = (float4*)ws;
    unsigned* cnt    = (unsigned*)(ws + CNT_OFF);

    hipMemsetAsync(cnt, 0, NB * sizeof(unsigned), stream);
    k_scatter<<<2048, 1024, 0, stream>>>(inp, grid, binned, cnt, out, n);
    k_gather <<<NB,   GBLK, 0, stream>>>(binned, grid, cnt, out);
}

// Round 9
// 157.729 us; speedup vs baseline: 1.4649x; 1.4628x over previous
//
#include <hip/hip_runtime.h>

// Trilinear feature-grid interpolation, v5 = round-5 front-end (measured
// ~60us: LDS-aggregated hist + scan + block-aggregated scatter, dense
// offsets) + round-7 back-end (measured ~80us: global_load_lds slab-staged
// gather), both on 64x8x8-cell bins (4096 bins).
// grid layout: [R][R][R][3] = [z][y][x][c], R=256, fp32 (192 MB).

#define NB     4096
#define GBLK   512
#define CHUNKF 196                // floats per x-chunk (49 float4)
#define NCHUNK 81                 // 9 z-rows x 9 y-rows
#define NF4    (NCHUNK * 49)      // 3969 float4 per slab
#define LDSF   (NF4 * 4)          // 15876 floats = 63504 B

// ws layout: binned[2^21] float4 = 32MB, then off[4097], cur[4096], hist[4096]
#define OFF_OFF   33554432u
#define CUR_OFF   (33554432u + 16388u)
#define HIST_OFF  (33554432u + 16388u + 16384u)
#define NEEDED    (33554432u + 65536u)

typedef float f4v __attribute__((ext_vector_type(4)));
typedef float f2v __attribute__((ext_vector_type(2)));
typedef f4v f4u __attribute__((aligned(8)));
typedef f2v f2u __attribute__((aligned(8)));

__device__ __forceinline__ void cell_of(float p, int& l, float& t) {
    float s = p * 255.0f;
    int v = (int)floorf(s);
    v = v < 0 ? 0 : (v > 254 ? 254 : v);
    l = v;
    t = s - (float)v;
}

// bin bits: [zb:5][yb:5][xb:2]  (64x8x8 cells per bin)
__device__ __forceinline__ int fine_bin3(float px, float py, float pz) {
    int xl, yl, zl; float tx, ty, tz;
    cell_of(px, xl, tx);
    cell_of(py, yl, ty);
    cell_of(pz, zl, tz);
    return ((((zl >> 3) << 5) | (yl >> 3)) << 2) | (xl >> 6);
}

// ---------------- pass 1: histogram (LDS-aggregated) ----------------
__global__ __launch_bounds__(1024) void k_hist(const float* __restrict__ inp,
                                               unsigned* __restrict__ hist, int n) {
    __shared__ unsigned h[NB];
    int t = threadIdx.x;
    for (int i = t; i < NB; i += 1024) h[i] = 0;
    __syncthreads();
    int stride = gridDim.x * 1024;
    for (int i = blockIdx.x * 1024 + t; i < n; i += stride)
        atomicAdd(&h[fine_bin3(inp[3 * i], inp[3 * i + 1], inp[3 * i + 2])], 1u);
    __syncthreads();
    for (int i = t; i < NB; i += 1024)
        if (h[i]) atomicAdd(&hist[i], h[i]);
}

// ---------------- pass 2: exclusive scan over 4096 ----------------
__global__ __launch_bounds__(1024) void k_scan(const unsigned* __restrict__ hist,
                                               unsigned* __restrict__ off,
                                               unsigned* __restrict__ cur) {
    __shared__ unsigned s[1024];
    int t = threadIdx.x;
    unsigned v0 = hist[4 * t], v1 = hist[4 * t + 1];
    unsigned v2 = hist[4 * t + 2], v3 = hist[4 * t + 3];
    unsigned sum = v0 + v1 + v2 + v3;
    s[t] = sum;
    __syncthreads();
    for (int d = 1; d < 1024; d <<= 1) {
        unsigned add = (t >= d) ? s[t - d] : 0u;
        __syncthreads();
        s[t] += add;
        __syncthreads();
    }
    unsigned excl = s[t] - sum;
    unsigned e0 = excl, e1 = excl + v0, e2 = e1 + v1, e3 = e2 + v2;
    off[4 * t] = e0;     cur[4 * t] = e0;
    off[4 * t + 1] = e1; cur[4 * t + 1] = e1;
    off[4 * t + 2] = e2; cur[4 * t + 2] = e2;
    off[4 * t + 3] = e3; cur[4 * t + 3] = e3;
    if (t == 1023) off[NB] = s[1023];
}

// ---------------- pass 3: block-aggregated scatter ----------------
__global__ __launch_bounds__(1024) void k_scatter(const float* __restrict__ inp,
                                                  float4* __restrict__ binned,
                                                  unsigned* __restrict__ cur, int n) {
    __shared__ unsigned cnt[NB];
    __shared__ unsigned base[NB];
    int t = threadIdx.x;
    int stride = gridDim.x * 1024;
    int iters = (n + stride - 1) / stride;
    for (int it = 0; it < iters; ++it) {
        int i = it * stride + blockIdx.x * 1024 + t;
        for (int k = t; k < NB; k += 1024) cnt[k] = 0;
        __syncthreads();
        int b = 0; unsigned r = 0; float px = 0, py = 0, pz = 0;
        bool valid = (i < n);
        if (valid) {
            px = inp[3 * i];
            py = inp[3 * i + 1];
            pz = inp[3 * i + 2];
            b = fine_bin3(px, py, pz);
            r = atomicAdd(&cnt[b], 1u);
        }
        __syncthreads();
        for (int k = t; k < NB; k += 1024)
            if (cnt[k]) base[k] = atomicAdd(&cur[k], cnt[k]);
        __syncthreads();
        if (valid) {
            float4 v;
            v.x = px; v.y = py; v.z = pz; v.w = __uint_as_float((unsigned)i);
            binned[base[b] + r] = v;
        }
        __syncthreads();
    }
}

// ---------------- pass 4: LDS-staged gather / trilerp ----------------
__global__ __launch_bounds__(GBLK) void k_gather(const float4* __restrict__ binned,
                                                 const float* __restrict__ grid,
                                                 const unsigned* __restrict__ off,
                                                 float* __restrict__ out) {
    __shared__ __align__(16) float slab[LDSF];
    int bin = blockIdx.x;
    int x0 = (bin & 3) << 6;          // 0,64,128,192
    int y0 = ((bin >> 2) & 31) << 3;  // 0..248
    int z0 = (bin >> 7) << 3;         // 0..248
    int t = threadIdx.x;

    unsigned start = off[bin], end = off[bin + 1];
    unsigned count = end - start;

    // Prefetch this thread's first point while staging is in flight.
    float4 v;
    if ((unsigned)t < count) v = binned[start + (unsigned)t];

    // Stage 3969 float4 (81 chunks x 49) as an LDS-linear stream via
    // global_load_lds: dest = wave-uniform base + lane*16 by construction.
    for (int u0 = 0; u0 < NF4; u0 += GBLK) {
        int u = u0 + t;
        if (u < NF4) {
            int chunk = u / 49;
            int j = u - chunk * 49;
            int zc = chunk / 9;
            int yc = chunk - zc * 9;
            int zg = z0 + zc; zg = zg > 255 ? 255 : zg;   // clamped rows unread
            int yg = y0 + yc; yg = yg > 255 ? 255 : yg;
            // x0=192,j=48 would read 16B past the grid; those floats are
            // never consumed -> clamp SOURCE only, LDS dest stays linear.
            int joff = (j == 48 && x0 == 192) ? 0 : (j << 2);
            const float* src = grid + (size_t)((zg << 16) | (yg << 8) | x0) * 3 + joff;
            __builtin_amdgcn_global_load_lds(
                (const __attribute__((address_space(1))) unsigned int*)src,
                (__attribute__((address_space(3))) unsigned int*)&slab[(size_t)u * 4],
                16, 0, 0);
        }
    }
    __syncthreads();

    unsigned p = (unsigned)t;
    while (p < count) {
        float px = v.x, py = v.y, pz = v.z;
        unsigned idx = __float_as_uint(v.w);
        p += (unsigned)GBLK;
        if (p < count) v = binned[start + p];   // prefetch next iteration

        int xl, yl, zl; float tx, ty, tz;
        cell_of(px, xl, tx);
        cell_of(py, yl, ty);
        cell_of(pz, zl, tz);
        int xc = xl - x0, yc = yl - y0, zc = zl - z0;

        int r0 = (zc * 9 + yc) * CHUNKF + xc * 3;
        int e = r0 & ~1;
        bool d = (r0 & 1) != 0;

#define SEG_READ(b, s)                                   \
        do {                                             \
            f2v q0 = *(const f2u*)(&slab[(b)]);          \
            f2v q1 = *(const f2u*)(&slab[(b) + 2]);      \
            f2v q2 = *(const f2u*)(&slab[(b) + 4]);      \
            f2v q3 = *(const f2u*)(&slab[(b) + 6]);      \
            s[0] = d ? q0.y : q0.x;                      \
            s[1] = d ? q1.x : q0.y;                      \
            s[2] = d ? q1.y : q1.x;                      \
            s[3] = d ? q2.x : q1.y;                      \
            s[4] = d ? q2.y : q2.x;                      \
            s[5] = d ? q3.x : q2.y;                      \
        } while (0)

        float s00[6], s01[6], s10[6], s11[6];
        SEG_READ(e,               s00);   // (zc,   yc)
        SEG_READ(e + CHUNKF,      s01);   // (zc,   yc+1)
        SEG_READ(e + 9 * CHUNKF,  s10);   // (zc+1, yc)
        SEG_READ(e + 10 * CHUNKF, s11);   // (zc+1, yc+1)
#undef SEG_READ

        float o[3];
#pragma unroll
        for (int c = 0; c < 3; ++c) {
            float c00 = s00[c] * (1.0f - tx) + s00[c + 3] * tx;
            float c01 = s01[c] * (1.0f - tx) + s01[c + 3] * tx;
            float c10 = s10[c] * (1.0f - tx) + s10[c + 3] * tx;
            float c11 = s11[c] * (1.0f - tx) + s11[c + 3] * tx;
            float c0 = c00 * (1.0f - ty) + c01 * ty;
            float c1 = c10 * (1.0f - ty) + c11 * ty;
            o[c] = c0 * (1.0f - tz) + c1 * tz;
        }
        float3 w; w.x = o[0]; w.y = o[1]; w.z = o[2];
        *(float3*)(out + 3 * (size_t)idx) = w;
    }
}

// ---------------- fallback: direct ----------------
__global__ __launch_bounds__(256) void k_direct(const float* __restrict__ inp,
                                                const float* __restrict__ grid,
                                                float* __restrict__ out, int n) {
    int i = blockIdx.x * blockDim.x + threadIdx.x;
    if (i >= n) return;
    int xl, yl, zl; float tx, ty, tz;
    cell_of(inp[3 * i + 0], xl, tx);
    cell_of(inp[3 * i + 1], yl, ty);
    cell_of(inp[3 * i + 2], zl, tz);
    int b00 = (zl * 65536 + yl * 256 + xl) * 3;
    int b01 = b00 + 768, b10 = b00 + 196608, b11 = b10 + 768;
    float s00[6], s01[6], s10[6], s11[6];
#pragma unroll
    for (int kk = 0; kk < 6; ++kk) s00[kk] = grid[b00 + kk];
#pragma unroll
    for (int kk = 0; kk < 6; ++kk) s01[kk] = grid[b01 + kk];
#pragma unroll
    for (int kk = 0; kk < 6; ++kk) s10[kk] = grid[b10 + kk];
#pragma unroll
    for (int kk = 0; kk < 6; ++kk) s11[kk] = grid[b11 + kk];
#pragma unroll
    for (int c = 0; c < 3; ++c) {
        float c00 = s00[c] * (1.0f - tx) + s00[c + 3] * tx;
        float c01 = s01[c] * (1.0f - tx) + s01[c + 3] * tx;
        float c10 = s10[c] * (1.0f - tx) + s10[c + 3] * tx;
        float c11 = s11[c] * (1.0f - tx) + s11[c + 3] * tx;
        float c0 = c00 * (1.0f - ty) + c01 * ty;
        float c1 = c10 * (1.0f - ty) + c11 * ty;
        out[3 * i + c] = c0 * (1.0f - tz) + c1 * tz;
    }
}

extern "C" void kernel_launch(void* const* d_in, const int* in_sizes, int n_in,
                              void* d_out, int out_size, void* d_ws, size_t ws_size,
                              hipStream_t stream) {
    const float* inp  = (const float*)d_in[0];  // [N][3]
    const float* grid = (const float*)d_in[1];  // [256][256][256][3]
    float* out = (float*)d_out;                 // [N][3]
    int n = in_sizes[0] / 3;

    if (ws_size < (size_t)NEEDED) {
        int blocks = (n + 255) / 256;
        k_direct<<<blocks, 256, 0, stream>>>(inp, grid, out, n);
        return;
    }

    char* ws = (char*)d_ws;
    float4*   binned = (float4*)ws;
    unsigned* off    = (unsigned*)(ws + OFF_OFF);
    unsigned* cur    = (unsigned*)(ws + CUR_OFF);
    unsigned* hist   = (unsigned*)(ws + HIST_OFF);

    hipMemsetAsync(hist, 0, NB * sizeof(unsigned), stream);
    k_hist   <<<256, 1024, 0, stream>>>(inp, hist, n);
    k_scan   <<<1,   1024, 0, stream>>>(hist, off, cur);
    k_scatter<<<256, 1024, 0, stream>>>(inp, binned, cur, n);
    k_gather <<<NB,  GBLK, 0, stream>>>(binned, grid, off, out);
}

// Round 10
// 146.917 us; speedup vs baseline: 1.5727x; 1.0736x over previous
//
#include <hip/hip_runtime.h>

// Trilinear feature-grid interpolation, v6.
// grid layout: [R][R][R][3] = [z][y][x][c], R=256, fp32 (192 MB).
//
// v5 (157.7us) = binning front-end + global_load_lds slab gather.
// v6 changes, per round-9 analysis:
//  - gather: bins 32x8x8 (8192 bins, slab 33x9x9 cells = 32.4 KB) ->
//    4 blocks/CU (was 2) for stage/compute overlap across blocks.
//  - front-end: 2 points/thread vectorized coord loads in hist+scatter;
//    k_zero kernel instead of hipMemsetAsync; scan widened to 8192.

#define NB     8192
#define GBLK   512
#define CHUNKF 100                // floats per x-chunk (25 float4; 99 used)
#define NCHUNK 81                 // 9 z-rows x 9 y-rows
#define NF4    2025               // 81*25 float4 per slab
#define LDSF   8100               // floats = 32400 B

// ws layout: binned[2^21] float4 = 32MB, then off[8193], cur[8192], hist[8192]
#define OFF_OFF   33554432u
#define CUR_OFF   (33554432u + 32772u)
#define HIST_OFF  (33554432u + 32772u + 32768u)
#define NEEDED    (33554432u + 32772u + 32768u + 32768u)

typedef float f4v __attribute__((ext_vector_type(4)));
typedef float f2v __attribute__((ext_vector_type(2)));
typedef f4v f4u __attribute__((aligned(8)));
typedef f2v f2u __attribute__((aligned(8)));

__device__ __forceinline__ void cell_of(float p, int& l, float& t) {
    float s = p * 255.0f;
    int v = (int)floorf(s);
    v = v < 0 ? 0 : (v > 254 ? 254 : v);
    l = v;
    t = s - (float)v;
}

// bin bits: [zb:5][yb:5][xb:3]  (32x8x8 cells per bin)
__device__ __forceinline__ int fine_bin3(float px, float py, float pz) {
    int xl, yl, zl; float tx, ty, tz;
    cell_of(px, xl, tx);
    cell_of(py, yl, ty);
    cell_of(pz, zl, tz);
    return ((zl >> 3) << 8) | ((yl >> 3) << 3) | (xl >> 5);
}

// ---------------- pass 0: zero hist ----------------
__global__ __launch_bounds__(1024) void k_zero(unsigned* __restrict__ hist) {
    int i = blockIdx.x * 1024 + threadIdx.x;
    if (i < NB) hist[i] = 0;
}

// ---------------- pass 1: histogram (2 pts/thread, LDS-aggregated) ----------------
__global__ __launch_bounds__(1024) void k_hist(const float* __restrict__ inp,
                                               unsigned* __restrict__ hist, int n) {
    __shared__ unsigned h[NB];
    int t = threadIdx.x;
    for (int i = t; i < NB; i += 1024) h[i] = 0;
    __syncthreads();
    int P = n >> 1;
    int stride = gridDim.x * 1024;
    for (int pr = blockIdx.x * 1024 + t; pr < P; pr += stride) {
        f4v a = *(const f4u*)(inp + 6 * pr);
        f2v b = *(const f2u*)(inp + 6 * pr + 4);
        atomicAdd(&h[fine_bin3(a.x, a.y, a.z)], 1u);
        atomicAdd(&h[fine_bin3(a.w, b.x, b.y)], 1u);
    }
    if ((n & 1) && blockIdx.x == 0 && t == 0) {
        int i = n - 1;
        atomicAdd(&hist[fine_bin3(inp[3 * i], inp[3 * i + 1], inp[3 * i + 2])], 1u);
    }
    __syncthreads();
    for (int i = t; i < NB; i += 1024)
        if (h[i]) atomicAdd(&hist[i], h[i]);
}

// ---------------- pass 2: exclusive scan over 8192 ----------------
__global__ __launch_bounds__(1024) void k_scan(const unsigned* __restrict__ hist,
                                               unsigned* __restrict__ off,
                                               unsigned* __restrict__ cur) {
    __shared__ unsigned s[1024];
    int t = threadIdx.x;
    unsigned v[8];
    unsigned sum = 0;
#pragma unroll
    for (int k = 0; k < 8; ++k) { v[k] = hist[8 * t + k]; sum += v[k]; }
    s[t] = sum;
    __syncthreads();
    for (int d = 1; d < 1024; d <<= 1) {
        unsigned add = (t >= d) ? s[t - d] : 0u;
        __syncthreads();
        s[t] += add;
        __syncthreads();
    }
    unsigned e = s[t] - sum;
#pragma unroll
    for (int k = 0; k < 8; ++k) {
        off[8 * t + k] = e;
        cur[8 * t + k] = e;
        e += v[k];
    }
    if (t == 1023) off[NB] = s[1023];
}

// ---------------- pass 3: block-aggregated scatter (2 pts/thread) ----------------
__global__ __launch_bounds__(1024) void k_scatter(const float* __restrict__ inp,
                                                  float4* __restrict__ binned,
                                                  unsigned* __restrict__ cur, int n) {
    __shared__ unsigned cnt[NB];
    __shared__ unsigned base[NB];
    int t = threadIdx.x;
    int P = n >> 1;
    int stride = gridDim.x * 1024;
    int iters = (P + stride - 1) / stride;

    if ((n & 1) && blockIdx.x == 0 && t == 0) {
        int i = n - 1;
        float px = inp[3 * i], py = inp[3 * i + 1], pz = inp[3 * i + 2];
        int b = fine_bin3(px, py, pz);
        unsigned r = atomicAdd(&cur[b], 1u);
        float4 v; v.x = px; v.y = py; v.z = pz; v.w = __uint_as_float((unsigned)i);
        binned[r] = v;
    }

    for (int it = 0; it < iters; ++it) {
        int pr = it * stride + blockIdx.x * 1024 + t;
        for (int k = t; k < NB; k += 1024) cnt[k] = 0;
        __syncthreads();
        int b0 = 0, b1 = 0; unsigned r0 = 0, r1 = 0;
        float4 p0, p1;
        bool valid = (pr < P);
        if (valid) {
            f4v a = *(const f4u*)(inp + 6 * pr);
            f2v b = *(const f2u*)(inp + 6 * pr + 4);
            p0.x = a.x; p0.y = a.y; p0.z = a.z;
            p0.w = __uint_as_float((unsigned)(2 * pr));
            p1.x = a.w; p1.y = b.x; p1.z = b.y;
            p1.w = __uint_as_float((unsigned)(2 * pr + 1));
            b0 = fine_bin3(p0.x, p0.y, p0.z);
            b1 = fine_bin3(p1.x, p1.y, p1.z);
            r0 = atomicAdd(&cnt[b0], 1u);
            r1 = atomicAdd(&cnt[b1], 1u);
        }
        __syncthreads();
        for (int k = t; k < NB; k += 1024)
            if (cnt[k]) base[k] = atomicAdd(&cur[k], cnt[k]);
        __syncthreads();
        if (valid) {
            binned[base[b0] + r0] = p0;
            binned[base[b1] + r1] = p1;
        }
        __syncthreads();
    }
}

// ---------------- pass 4: LDS-staged gather / trilerp ----------------
__global__ __launch_bounds__(GBLK, 8) void k_gather(const float4* __restrict__ binned,
                                                    const float* __restrict__ grid,
                                                    const unsigned* __restrict__ off,
                                                    float* __restrict__ out) {
    __shared__ __align__(16) float slab[LDSF];
    int bin = blockIdx.x;
    int x0 = (bin & 7) << 5;          // 0,32,..,224
    int y0 = ((bin >> 3) & 31) << 3;  // 0..248
    int z0 = (bin >> 8) << 3;         // 0..248
    int t = threadIdx.x;

    unsigned start = off[bin], end = off[bin + 1];
    unsigned count = end - start;

    // Prefetch this thread's first point while staging is in flight.
    float4 v;
    if ((unsigned)t < count) v = binned[start + (unsigned)t];

    // Stage 2025 float4 (81 chunks x 25) as an LDS-linear stream via
    // global_load_lds (dest = wave-uniform base + lane*16 by construction).
    for (int u = t; u < NF4; u += GBLK) {
        int chunk = u / 25;
        int j = u - chunk * 25;
        int zc = chunk / 9;
        int yc = chunk - zc * 9;
        int zg = z0 + zc; zg = zg > 255 ? 255 : zg;   // clamped rows never read
        int yg = y0 + yc; yg = yg > 255 ? 255 : yg;
        // x0=224,j=24 would read past row end (cells >=256 / OOB at the very
        // last chunk); those floats are never selected (xl<=254 -> xc<=30)
        // -> clamp SOURCE only, LDS dest stays linear.
        int joff = (j == 24 && x0 == 224) ? 0 : (j << 2);
        const float* src = grid + (size_t)((zg << 16) | (yg << 8) | x0) * 3 + joff;
        __builtin_amdgcn_global_load_lds(
            (const __attribute__((address_space(1))) unsigned int*)src,
            (__attribute__((address_space(3))) unsigned int*)&slab[(size_t)u * 4],
            16, 0, 0);
    }
    __syncthreads();

    unsigned p = (unsigned)t;
    while (p < count) {
        float px = v.x, py = v.y, pz = v.z;
        unsigned idx = __float_as_uint(v.w);
        p += (unsigned)GBLK;
        if (p < count) v = binned[start + p];   // prefetch next iteration

        int xl, yl, zl; float tx, ty, tz;
        cell_of(px, xl, tx);
        cell_of(py, yl, ty);
        cell_of(pz, zl, tz);
        int xc = xl - x0, yc = yl - y0, zc = zl - z0;

        int r0 = (zc * 9 + yc) * CHUNKF + xc * 3;
        int e = r0 & ~1;
        bool d = (r0 & 1) != 0;

#define SEG_READ(b, s)                                   \
        do {                                             \
            f2v q0 = *(const f2u*)(&slab[(b)]);          \
            f2v q1 = *(const f2u*)(&slab[(b) + 2]);      \
            f2v q2 = *(const f2u*)(&slab[(b) + 4]);      \
            f2v q3 = *(const f2u*)(&slab[(b) + 6]);      \
            s[0] = d ? q0.y : q0.x;                      \
            s[1] = d ? q1.x : q0.y;                      \
            s[2] = d ? q1.y : q1.x;                      \
            s[3] = d ? q2.x : q1.y;                      \
            s[4] = d ? q2.y : q2.x;                      \
            s[5] = d ? q3.x : q2.y;                      \
        } while (0)

        float s00[6], s01[6], s10[6], s11[6];
        SEG_READ(e,               s00);   // (zc,   yc)
        SEG_READ(e + CHUNKF,      s01);   // (zc,   yc+1)
        SEG_READ(e + 9 * CHUNKF,  s10);   // (zc+1, yc)
        SEG_READ(e + 10 * CHUNKF, s11);   // (zc+1, yc+1)
#undef SEG_READ

        float o[3];
#pragma unroll
        for (int c = 0; c < 3; ++c) {
            float c00 = s00[c] * (1.0f - tx) + s00[c + 3] * tx;
            float c01 = s01[c] * (1.0f - tx) + s01[c + 3] * tx;
            float c10 = s10[c] * (1.0f - tx) + s10[c + 3] * tx;
            float c11 = s11[c] * (1.0f - tx) + s11[c + 3] * tx;
            float c0 = c00 * (1.0f - ty) + c01 * ty;
            float c1 = c10 * (1.0f - ty) + c11 * ty;
            o[c] = c0 * (1.0f - tz) + c1 * tz;
        }
        float3 w; w.x = o[0]; w.y = o[1]; w.z = o[2];
        *(float3*)(out + 3 * (size_t)idx) = w;
    }
}

// ---------------- fallback: direct ----------------
__global__ __launch_bounds__(256) void k_direct(const float* __restrict__ inp,
                                                const float* __restrict__ grid,
                                                float* __restrict__ out, int n) {
    int i = blockIdx.x * blockDim.x + threadIdx.x;
    if (i >= n) return;
    int xl, yl, zl; float tx, ty, tz;
    cell_of(inp[3 * i + 0], xl, tx);
    cell_of(inp[3 * i + 1], yl, ty);
    cell_of(inp[3 * i + 2], zl, tz);
    int b00 = (zl * 65536 + yl * 256 + xl) * 3;
    int b01 = b00 + 768, b10 = b00 + 196608, b11 = b10 + 768;
    float s00[6], s01[6], s10[6], s11[6];
#pragma unroll
    for (int kk = 0; kk < 6; ++kk) s00[kk] = grid[b00 + kk];
#pragma unroll
    for (int kk = 0; kk < 6; ++kk) s01[kk] = grid[b01 + kk];
#pragma unroll
    for (int kk = 0; kk < 6; ++kk) s10[kk] = grid[b10 + kk];
#pragma unroll
    for (int kk = 0; kk < 6; ++kk) s11[kk] = grid[b11 + kk];
#pragma unroll
    for (int c = 0; c < 3; ++c) {
        float c00 = s00[c] * (1.0f - tx) + s00[c + 3] * tx;
        float c01 = s01[c] * (1.0f - tx) + s01[c + 3] * tx;
        float c10 = s10[c] * (1.0f - tx) + s10[c + 3] * tx;
        float c11 = s11[c] * (1.0f - tx) + s11[c + 3] * tx;
        float c0 = c00 * (1.0f - ty) + c01 * ty;
        float c1 = c10 * (1.0f - ty) + c11 * ty;
        out[3 * i + c] = c0 * (1.0f - tz) + c1 * tz;
    }
}

extern "C" void kernel_launch(void* const* d_in, const int* in_sizes, int n_in,
                              void* d_out, int out_size, void* d_ws, size_t ws_size,
                              hipStream_t stream) {
    const float* inp  = (const float*)d_in[0];  // [N][3]
    const float* grid = (const float*)d_in[1];  // [256][256][256][3]
    float* out = (float*)d_out;                 // [N][3]
    int n = in_sizes[0] / 3;

    if (ws_size < (size_t)NEEDED) {
        int blocks = (n + 255) / 256;
        k_direct<<<blocks, 256, 0, stream>>>(inp, grid, out, n);
        return;
    }

    char* ws = (char*)d_ws;
    float4*   binned = (float4*)ws;
    unsigned* off    = (unsigned*)(ws + OFF_OFF);
    unsigned* cur    = (unsigned*)(ws + CUR_OFF);
    unsigned* hist   = (unsigned*)(ws + HIST_OFF);

    k_zero   <<<8,   1024, 0, stream>>>(hist);
    k_hist   <<<256, 1024, 0, stream>>>(inp, hist, n);
    k_scan   <<<1,   1024, 0, stream>>>(hist, off, cur);
    k_scatter<<<256, 1024, 0, stream>>>(inp, binned, cur, n);
    k_gather <<<NB,  GBLK, 0, stream>>>(binned, grid, off, out);
}

// Round 11
// 141.384 us; speedup vs baseline: 1.6342x; 1.0391x over previous
//
#include <hip/hip_runtime.h>

// Trilinear feature-grid interpolation, v7.
// grid layout: [R][R][R][3] = [z][y][x][c], R=256, fp32 (192 MB).
//
// v6 (146.9us) = zero+hist+scan+scatter+gather.
// v7: ws is ~768MB -> fixed-capacity CAP-strided bins (8192 x 512 x 16B =
// 64MB) remove hist/scan/zero entirely; scatter keeps the measured-good
// block-aggregated LDS-count structure (round 7 showed PER-POINT global
// atomics at 150us; round 9 showed block-agg+dense fast; this round tests
// block-agg+sparse). k_gather adds an XCD-chunked bin swizzle so slab
// borders shared by y/z-adjacent bins hit the same XCD's L2.

#define NB     8192
#define CAP    512u
#define GBLK   512
#define CHUNKF 100                // floats per x-chunk (25 float4; 99 used)
#define NCHUNK 81                 // 9 z-rows x 9 y-rows
#define NF4    2025               // 81*25 float4 per slab
#define LDSF   8100               // floats = 32400 B

// ws layout: binned[8192*512] float4 = 64MB, then cur[8192]
#define CUR_OFF   67108864u
#define NEEDED    (67108864u + 32768u)

typedef float f4v __attribute__((ext_vector_type(4)));
typedef float f2v __attribute__((ext_vector_type(2)));
typedef f4v f4u __attribute__((aligned(8)));
typedef f2v f2u __attribute__((aligned(8)));

__device__ __forceinline__ void cell_of(float p, int& l, float& t) {
    float s = p * 255.0f;
    int v = (int)floorf(s);
    v = v < 0 ? 0 : (v > 254 ? 254 : v);
    l = v;
    t = s - (float)v;
}

// bin bits: [zb:5][yb:5][xb:3]  (32x8x8 cells per bin)
__device__ __forceinline__ int fine_bin3(float px, float py, float pz) {
    int xl, yl, zl; float tx, ty, tz;
    cell_of(px, xl, tx);
    cell_of(py, yl, ty);
    cell_of(pz, zl, tz);
    return ((zl >> 3) << 8) | ((yl >> 3) << 3) | (xl >> 5);
}

__device__ __forceinline__ void direct_lerp(const float* __restrict__ grid,
                                            float* __restrict__ out, int i,
                                            int xl, int yl, int zl,
                                            float tx, float ty, float tz) {
    int b00 = (zl * 65536 + yl * 256 + xl) * 3;
    int b01 = b00 + 768, b10 = b00 + 196608, b11 = b10 + 768;
    float s00[6], s01[6], s10[6], s11[6];
#pragma unroll
    for (int k = 0; k < 6; ++k) s00[k] = grid[b00 + k];
#pragma unroll
    for (int k = 0; k < 6; ++k) s01[k] = grid[b01 + k];
#pragma unroll
    for (int k = 0; k < 6; ++k) s10[k] = grid[b10 + k];
#pragma unroll
    for (int k = 0; k < 6; ++k) s11[k] = grid[b11 + k];
#pragma unroll
    for (int c = 0; c < 3; ++c) {
        float c00 = s00[c] * (1.0f - tx) + s00[c + 3] * tx;
        float c01 = s01[c] * (1.0f - tx) + s01[c + 3] * tx;
        float c10 = s10[c] * (1.0f - tx) + s10[c + 3] * tx;
        float c11 = s11[c] * (1.0f - tx) + s11[c + 3] * tx;
        float c0 = c00 * (1.0f - ty) + c01 * ty;
        float c1 = c10 * (1.0f - ty) + c11 * ty;
        out[3 * i + c] = c0 * (1.0f - tz) + c1 * tz;
    }
}

// ---------------- pass 0: init cursors to region bases ----------------
__global__ __launch_bounds__(1024) void k_init(unsigned* __restrict__ cur) {
    int i = blockIdx.x * 1024 + threadIdx.x;
    if (i < NB) cur[i] = (unsigned)i * CAP;
}

// ---------------- pass 1: block-aggregated scatter (2 pts/thread) ----------------
__global__ __launch_bounds__(1024) void k_scatter(const float* __restrict__ inp,
                                                  const float* __restrict__ grid,
                                                  float4* __restrict__ binned,
                                                  unsigned* __restrict__ cur,
                                                  float* __restrict__ out, int n) {
    __shared__ unsigned cnt[NB];
    __shared__ unsigned base[NB];
    int t = threadIdx.x;
    int P = n >> 1;
    int stride = gridDim.x * 1024;
    int iters = (P + stride - 1) / stride;

    if ((n & 1) && blockIdx.x == 0 && t == 0) {
        int i = n - 1;
        float px = inp[3 * i], py = inp[3 * i + 1], pz = inp[3 * i + 2];
        int b = fine_bin3(px, py, pz);
        unsigned r = atomicAdd(&cur[b], 1u);
        if (r - (unsigned)b * CAP < CAP) {
            float4 v; v.x = px; v.y = py; v.z = pz; v.w = __uint_as_float((unsigned)i);
            binned[r] = v;
        } else {
            int xl, yl, zl; float tx, ty, tz;
            cell_of(px, xl, tx); cell_of(py, yl, ty); cell_of(pz, zl, tz);
            direct_lerp(grid, out, i, xl, yl, zl, tx, ty, tz);
        }
    }

    for (int it = 0; it < iters; ++it) {
        int pr = it * stride + blockIdx.x * 1024 + t;
        for (int k = t; k < NB; k += 1024) cnt[k] = 0;
        __syncthreads();
        int b0 = 0, b1 = 0; unsigned r0 = 0, r1 = 0;
        float4 p0, p1;
        bool valid = (pr < P);
        if (valid) {
            f4v a = *(const f4u*)(inp + 6 * pr);
            f2v b = *(const f2u*)(inp + 6 * pr + 4);
            p0.x = a.x; p0.y = a.y; p0.z = a.z;
            p0.w = __uint_as_float((unsigned)(2 * pr));
            p1.x = a.w; p1.y = b.x; p1.z = b.y;
            p1.w = __uint_as_float((unsigned)(2 * pr + 1));
            b0 = fine_bin3(p0.x, p0.y, p0.z);
            b1 = fine_bin3(p1.x, p1.y, p1.z);
            r0 = atomicAdd(&cnt[b0], 1u);
            r1 = atomicAdd(&cnt[b1], 1u);
        }
        __syncthreads();
        for (int k = t; k < NB; k += 1024)
            if (cnt[k]) base[k] = atomicAdd(&cur[k], cnt[k]);
        __syncthreads();
        if (valid) {
            unsigned s0 = base[b0] + r0;
            unsigned s1 = base[b1] + r1;
            if (s0 - (unsigned)b0 * CAP < CAP) binned[s0] = p0;
            else {
                int xl, yl, zl; float tx, ty, tz;
                cell_of(p0.x, xl, tx); cell_of(p0.y, yl, ty); cell_of(p0.z, zl, tz);
                direct_lerp(grid, out, 2 * pr, xl, yl, zl, tx, ty, tz);
            }
            if (s1 - (unsigned)b1 * CAP < CAP) binned[s1] = p1;
            else {
                int xl, yl, zl; float tx, ty, tz;
                cell_of(p1.x, xl, tx); cell_of(p1.y, yl, ty); cell_of(p1.z, zl, tz);
                direct_lerp(grid, out, 2 * pr + 1, xl, yl, zl, tx, ty, tz);
            }
        }
        __syncthreads();
    }
}

// ---------------- pass 2: LDS-staged gather / trilerp ----------------
__global__ __launch_bounds__(GBLK, 8) void k_gather(const float4* __restrict__ binned,
                                                    const float* __restrict__ grid,
                                                    const unsigned* __restrict__ cur,
                                                    float* __restrict__ out) {
    __shared__ __align__(16) float slab[LDSF];
    // XCD-chunked swizzle: blockIdx%8 == XCD k -> bins [1024k, 1024k+1024),
    // processed in ascending order, so y/z-adjacent bins' shared slab rows
    // hit the same XCD's L2. Bijective (8192 = 8*1024).
    int bin = ((blockIdx.x & 7) << 10) | (blockIdx.x >> 3);
    int x0 = (bin & 7) << 5;          // 0,32,..,224
    int y0 = ((bin >> 3) & 31) << 3;  // 0..248
    int z0 = (bin >> 8) << 3;         // 0..248
    int t = threadIdx.x;

    unsigned start = (unsigned)bin * CAP;
    unsigned count = cur[bin] - start;
    if (count > CAP) count = CAP;

    // Prefetch this thread's first point while staging is in flight.
    float4 v;
    if ((unsigned)t < count) v = binned[start + (unsigned)t];

    // Stage 2025 float4 (81 chunks x 25) as an LDS-linear stream via
    // global_load_lds (dest = wave-uniform base + lane*16 by construction).
    for (int u = t; u < NF4; u += GBLK) {
        int chunk = u / 25;
        int j = u - chunk * 25;
        int zc = chunk / 9;
        int yc = chunk - zc * 9;
        int zg = z0 + zc; zg = zg > 255 ? 255 : zg;   // clamped rows never read
        int yg = y0 + yc; yg = yg > 255 ? 255 : yg;
        // x0=224,j=24 would read past row end; those floats are never
        // selected (xl<=254 -> xc<=30) -> clamp SOURCE only, dest stays linear.
        int joff = (j == 24 && x0 == 224) ? 0 : (j << 2);
        const float* src = grid + (size_t)((zg << 16) | (yg << 8) | x0) * 3 + joff;
        __builtin_amdgcn_global_load_lds(
            (const __attribute__((address_space(1))) unsigned int*)src,
            (__attribute__((address_space(3))) unsigned int*)&slab[(size_t)u * 4],
            16, 0, 0);
    }
    __syncthreads();

    unsigned p = (unsigned)t;
    while (p < count) {
        float px = v.x, py = v.y, pz = v.z;
        unsigned idx = __float_as_uint(v.w);
        p += (unsigned)GBLK;
        if (p < count) v = binned[start + p];   // prefetch next iteration

        int xl, yl, zl; float tx, ty, tz;
        cell_of(px, xl, tx);
        cell_of(py, yl, ty);
        cell_of(pz, zl, tz);
        int xc = xl - x0, yc = yl - y0, zc = zl - z0;

        int r0 = (zc * 9 + yc) * CHUNKF + xc * 3;
        int e = r0 & ~1;
        bool d = (r0 & 1) != 0;

#define SEG_READ(b, s)                                   \
        do {                                             \
            f2v q0 = *(const f2u*)(&slab[(b)]);          \
            f2v q1 = *(const f2u*)(&slab[(b) + 2]);      \
            f2v q2 = *(const f2u*)(&slab[(b) + 4]);      \
            f2v q3 = *(const f2u*)(&slab[(b) + 6]);      \
            s[0] = d ? q0.y : q0.x;                      \
            s[1] = d ? q1.x : q0.y;                      \
            s[2] = d ? q1.y : q1.x;                      \
            s[3] = d ? q2.x : q1.y;                      \
            s[4] = d ? q2.y : q2.x;                      \
            s[5] = d ? q3.x : q2.y;                      \
        } while (0)

        float s00[6], s01[6], s10[6], s11[6];
        SEG_READ(e,               s00);   // (zc,   yc)
        SEG_READ(e + CHUNKF,      s01);   // (zc,   yc+1)
        SEG_READ(e + 9 * CHUNKF,  s10);   // (zc+1, yc)
        SEG_READ(e + 10 * CHUNKF, s11);   // (zc+1, yc+1)
#undef SEG_READ

        float o[3];
#pragma unroll
        for (int c = 0; c < 3; ++c) {
            float c00 = s00[c] * (1.0f - tx) + s00[c + 3] * tx;
            float c01 = s01[c] * (1.0f - tx) + s01[c + 3] * tx;
            float c10 = s10[c] * (1.0f - tx) + s10[c + 3] * tx;
            float c11 = s11[c] * (1.0f - tx) + s11[c + 3] * tx;
            float c0 = c00 * (1.0f - ty) + c01 * ty;
            float c1 = c10 * (1.0f - ty) + c11 * ty;
            o[c] = c0 * (1.0f - tz) + c1 * tz;
        }
        float3 w; w.x = o[0]; w.y = o[1]; w.z = o[2];
        *(float3*)(out + 3 * (size_t)idx) = w;
    }
}

// ---------------- fallback: direct ----------------
__global__ __launch_bounds__(256) void k_direct(const float* __restrict__ inp,
                                                const float* __restrict__ grid,
                                                float* __restrict__ out, int n) {
    int i = blockIdx.x * blockDim.x + threadIdx.x;
    if (i >= n) return;
    int xl, yl, zl; float tx, ty, tz;
    cell_of(inp[3 * i + 0], xl, tx);
    cell_of(inp[3 * i + 1], yl, ty);
    cell_of(inp[3 * i + 2], zl, tz);
    direct_lerp(grid, out, i, xl, yl, zl, tx, ty, tz);
}

extern "C" void kernel_launch(void* const* d_in, const int* in_sizes, int n_in,
                              void* d_out, int out_size, void* d_ws, size_t ws_size,
                              hipStream_t stream) {
    const float* inp  = (const float*)d_in[0];  // [N][3]
    const float* grid = (const float*)d_in[1];  // [256][256][256][3]
    float* out = (float*)d_out;                 // [N][3]
    int n = in_sizes[0] / 3;

    if (ws_size < (size_t)NEEDED) {
        int blocks = (n + 255) / 256;
        k_direct<<<blocks, 256, 0, stream>>>(inp, grid, out, n);
        return;
    }

    char* ws = (char*)d_ws;
    float4*   binned = (float4*)ws;
    unsigned* cur    = (unsigned*)(ws + CUR_OFF);

    k_init   <<<8,   1024, 0, stream>>>(cur);
    k_scatter<<<256, 1024, 0, stream>>>(inp, grid, binned, cur, out, n);
    k_gather <<<NB,  GBLK, 0, stream>>>(binned, grid, cur, out);
}